// Round 4
// baseline (116.866 us; speedup 1.0000x reference)
//
#include <hip/hip_runtime.h>
#include <hip/hip_bf16.h>
#include <cstdint>
#include <cstddef>

typedef _Float16 f16x8 __attribute__((ext_vector_type(8)));
typedef _Float16 f16x4 __attribute__((ext_vector_type(4)));
typedef float    f32x4 __attribute__((ext_vector_type(4)));

#define MFMA16(a,b,c) __builtin_amdgcn_mfma_f32_16x16x32_f16((a),(b),(c),0,0,0)

// Workspace layout (_Float16 elements):
//   W1T  [15][64][256] at 0        (245760)
//   W16T [64][384]     at 245760   (24576)   sp: x col = 1816+sp; zero for sp<4 or sp>=360
//   W2T  [4][64][256]  at 270336   (65536)
//   W3T  [272][256]    at 335872   (69632)   rows >= 260 zero
//   Y    [16384][1024] at 405504   (16777216)  layer-1 output (fused path only)
__global__ void tea_prep(const float* __restrict__ W1, const float* __restrict__ W16,
                         const float* __restrict__ W2, const float* __restrict__ W3,
                         _Float16* __restrict__ ws)
{
    int i = blockIdx.x * blockDim.x + threadIdx.x;
    if (i < 245760) {
        int k = i >> 14, r = i & 16383, o = r >> 8, s = r & 255;
        ws[i] = (_Float16)W1[((k << 8) | s) * 64 + o];
    } else if (i < 270336) {
        int r = i - 245760, o = r / 384, sp = r - o * 384;
        float v = (sp >= 4 && sp < 360) ? W16[(sp - 4) * 64 + o] : 0.f;
        ws[i] = (_Float16)v;
    } else if (i < 335872) {
        int r = i - 270336, g = r >> 14, rr = r & 16383, o = rr >> 8, s = rr & 255;
        ws[i] = (_Float16)W2[((g << 8) | s) * 64 + o];
    } else if (i < 405504) {
        int r = i - 335872, o = r >> 8, s = r & 255;
        ws[i] = (_Float16)((o < 260) ? W3[s * 260 + o] : 0.f);
    }
}

// ---------------- layer 1, windows 0..14 ----------------
// block = (window, 64-row tile); 4 waves x (16 rows x 64 outs), K=256.
// A: global x -> regs (cvt fp32->fp16).  B: W1T tile staged once in LDS [64][264].
__global__ __launch_bounds__(256, 4)
void tea_l1(const float* __restrict__ x, const float* __restrict__ b1,
            const _Float16* __restrict__ ws, _Float16* __restrict__ y)
{
    __shared__ _Float16 bsm[64 * 264];
    int bid = blockIdx.x;
    int wg  = (bid & 7) * 480 + (bid >> 3);      // bijective XCD swizzle (3840 % 8 == 0)
    int win = wg % 15, tile = wg / 15;
    int tid = threadIdx.x;
    int w = tid >> 6, l = tid & 63, lg = l >> 4, lr = l & 15;
    int rowbase = tile * 64 + w * 16;
    const _Float16* bw = ws + win * 16384;

    // stage W1T[win] (32 KB): thread -> row tid>>2, 128B seg tid&3
    {
        int row = tid >> 2, seg = tid & 3;
        const _Float16* s = bw + row * 256 + seg * 64;
        _Float16*       d = bsm + row * 264 + seg * 64;
        #pragma unroll
        for (int i = 0; i < 8; ++i) *(f16x8*)(d + i * 8) = *(const f16x8*)(s + i * 8);
    }

    // A: 16 rows x 256 k  (issued before the barrier; barrier drain covers them)
    const float* xr = x + (size_t)(rowbase + lr) * 2176 + win * 128;
    f16x8 a[8];
    #pragma unroll
    for (int kk = 0; kk < 8; ++kk) {
        const float* p = xr + kk * 32 + lg * 8;
        float4 u = *(const float4*)p;
        float4 v = *(const float4*)(p + 4);
        f16x8 h;
        h[0]=(_Float16)u.x; h[1]=(_Float16)u.y; h[2]=(_Float16)u.z; h[3]=(_Float16)u.w;
        h[4]=(_Float16)v.x; h[5]=(_Float16)v.y; h[6]=(_Float16)v.z; h[7]=(_Float16)v.w;
        a[kk] = h;
    }
    __syncthreads();

    const float* bias = b1 + win * 64;
    _Float16* yb = y + (size_t)(rowbase + lg * 4) * 1024 + win * 64 + lr;

    #pragma unroll
    for (int t = 0; t < 4; ++t) {
        f32x4 acc = {0.f, 0.f, 0.f, 0.f};
        const _Float16* br = bsm + (t * 16 + lr) * 264 + lg * 8;
        #pragma unroll
        for (int kk = 0; kk < 8; ++kk) {
            f16x8 B = *(const f16x8*)(br + kk * 32);
            acc = MFMA16(a[kk], B, acc);
        }
        float bv = bias[t * 16 + lr];
        #pragma unroll
        for (int j = 0; j < 4; ++j) {
            float v = acc[j] + bv; v = v > 0.f ? v : 0.f;
            yb[(size_t)j * 1024 + t * 16] = (_Float16)v;
        }
    }
}

// ---------------- layer 1, tail window (y16) ----------------
// 256 blocks (row tiles); K=384 (zero-padded); x col clamp only touches zero-weighted k.
__global__ __launch_bounds__(256, 2)
void tea_l1b(const float* __restrict__ x, const float* __restrict__ b16,
             const _Float16* __restrict__ ws, _Float16* __restrict__ y)
{
    int tile = blockIdx.x;
    int tid = threadIdx.x;
    int w = tid >> 6, l = tid & 63, lg = l >> 4, lr = l & 15;
    int rowbase = tile * 64 + w * 16;
    const float* xr = x + (size_t)(rowbase + lr) * 2176;
    const _Float16* wsW16 = ws + 245760;

    f16x8 a[12];
    #pragma unroll
    for (int kk = 0; kk < 12; ++kk) {
        int c0 = 1816 + kk * 32 + lg * 8;
        int c1 = c0 + 4;
        if (c0 >= 2176) c0 = 2168;     // only hits zero-weighted k (sp>=360)
        if (c1 >= 2176) c1 = 2168;
        float4 u = *(const float4*)(xr + c0);
        float4 v = *(const float4*)(xr + c1);
        f16x8 h;
        h[0]=(_Float16)u.x; h[1]=(_Float16)u.y; h[2]=(_Float16)u.z; h[3]=(_Float16)u.w;
        h[4]=(_Float16)v.x; h[5]=(_Float16)v.y; h[6]=(_Float16)v.z; h[7]=(_Float16)v.w;
        a[kk] = h;
    }
    _Float16* yb = y + (size_t)(rowbase + lg * 4) * 1024 + 960 + lr;
    #pragma unroll
    for (int t = 0; t < 4; ++t) {
        const _Float16* bp = wsW16 + (size_t)(t * 16 + lr) * 384 + lg * 8;
        f32x4 acc = {0.f, 0.f, 0.f, 0.f};
        #pragma unroll
        for (int kk = 0; kk < 12; ++kk) {
            f16x8 B = *(const f16x8*)(bp + kk * 32);
            acc = MFMA16(a[kk], B, acc);
        }
        float bv = b16[t * 16 + lr];
        #pragma unroll
        for (int j = 0; j < 4; ++j) {
            float v = acc[j] + bv; v = v > 0.f ? v : 0.f;
            yb[(size_t)j * 1024 + t * 16] = (_Float16)v;
        }
    }
}

// ---------------- layers 2+3 + pool + softmax ----------------
// 1024 blocks x 16 rows.  A(layer2) straight from y; z via LDS; B from L2.
__global__ __launch_bounds__(256, 4)
void tea_l2(const _Float16* __restrict__ y,
            const float* __restrict__ b2, const float* __restrict__ b3,
            const _Float16* __restrict__ ws, float* __restrict__ out)
{
    __shared__ _Float16 zsm[16 * 264];
    __shared__ float    hsm[16 * 280];
    int bid = blockIdx.x;
    int wg  = (bid & 7) * 128 + (bid >> 3);      // match l1's row->XCD mapping
    int tid = threadIdx.x;
    int w = tid >> 6, l = tid & 63, lg = l >> 4, lr = l & 15;
    const _Float16* wsW2 = ws + 270336;
    const _Float16* wsW3 = ws + 335872;
    const _Float16* yr = y + (size_t)(wg * 16 + lr) * 1024;

    #pragma unroll
    for (int g = 0; g < 4; ++g) {
        const _Float16* ap = yr + g * 256 + lg * 8;
        const _Float16* bp = wsW2 + g * 16384 + (size_t)(w * 16 + lr) * 256 + lg * 8;
        f16x8 A[8], B[8];
        #pragma unroll
        for (int i = 0; i < 8; ++i) A[i] = *(const f16x8*)(ap + i * 32);
        #pragma unroll
        for (int i = 0; i < 8; ++i) B[i] = *(const f16x8*)(bp + i * 32);
        f32x4 acc = {0.f, 0.f, 0.f, 0.f};
        #pragma unroll
        for (int kk = 0; kk < 8; ++kk) acc = MFMA16(A[kk], B[kk], acc);
        float bv = b2[g * 64 + w * 16 + lr];
        #pragma unroll
        for (int j = 0; j < 4; ++j) {
            float v = acc[j] + bv; v = v > 0.f ? v : 0.f;
            zsm[(lg * 4 + j) * 264 + g * 64 + w * 16 + lr] = (_Float16)v;
        }
    }
    __syncthreads();
    {
        f16x8 az[8];
        #pragma unroll
        for (int kk = 0; kk < 8; ++kk)
            az[kk] = *(const f16x8*)(zsm + lr * 264 + kk * 32 + lg * 8);
        #pragma unroll 1
        for (int t = w; t < 17; t += 4) {
            f32x4 acc = {0.f, 0.f, 0.f, 0.f};
            #pragma unroll
            for (int kk = 0; kk < 8; ++kk) {
                f16x8 B = *(const f16x8*)(wsW3 + (size_t)(t * 16 + lr) * 256 + kk * 32 + lg * 8);
                acc = MFMA16(az[kk], B, acc);
            }
            int o = t * 16 + lr;
            float bv = (o < 260) ? b3[o] : 0.f;
            #pragma unroll
            for (int j = 0; j < 4; ++j) {
                float v = acc[j] + bv; v = v > 0.f ? v : 0.f;
                hsm[(lg * 4 + j) * 280 + o] = v;
            }
        }
    }
    __syncthreads();
    if (tid < 16) {
        float p[10];
        #pragma unroll
        for (int c = 0; c < 10; ++c) {
            float s = 0.f;
            #pragma unroll
            for (int u = 0; u < 26; ++u) s += hsm[tid * 280 + c * 26 + u];
            p[c] = s;
        }
        float m = p[0];
        #pragma unroll
        for (int c = 1; c < 10; ++c) m = fmaxf(m, p[c]);
        float e[10], se = 0.f;
        #pragma unroll
        for (int c = 0; c < 10; ++c) { e[c] = expf(p[c] - m); se += e[c]; }
        float inv = 1.f / se;
        float* orow = out + (size_t)(wg * 16 + tid) * 10;
        #pragma unroll
        for (int c = 0; c < 10; ++c) orow[c] = e[c] * inv;
    }
}

// ---------------- fallback monolith (R3) if ws too small for Y ----------------
__global__ __launch_bounds__(256, 2)
void tea_mono(const float* __restrict__ x,
              const float* __restrict__ b1,
              const float* __restrict__ b16,
              const float* __restrict__ b2,
              const float* __restrict__ b3,
              const _Float16* __restrict__ ws,
              float* __restrict__ out)
{
    __shared__ _Float16 lds[34304];
    _Float16* xch = lds;
    _Float16* ysm = lds + 17408;
    _Float16* zsm = lds + 25856;
    float*    hsm = (float*)lds;

    const int tid = threadIdx.x;
    const int bid = blockIdx.x;
    const int w  = tid >> 6;
    const int l  = tid & 63;
    const int lg = l >> 4;
    const int lr = l & 15;

    const _Float16* wsW1  = ws;
    const _Float16* wsW16 = ws + 245760;
    const _Float16* wsW2  = ws + 270336;
    const _Float16* wsW3  = ws + 335872;

    const float* xrow = x + (size_t)bid * 32 * 2176;
    const int cr_row = tid >> 3;
    const int cr_col = (tid & 7) * 16;

    float4 creg[4][4];
    f16x8  Ba[8], Bb[8];
    f32x4  acc0, acc1;

#define PH_TOP() do { \
    asm volatile("s_waitcnt lgkmcnt(0)" ::: "memory"); \
    __builtin_amdgcn_s_barrier(); \
    __builtin_amdgcn_sched_barrier(0); } while (0)
#define ISSUE(C) do { \
    const float* _p = xrow + (size_t)cr_row * 2176 + (C) * 128 + cr_col; \
    creg[(C) & 3][0] = *(const float4*)(_p); \
    creg[(C) & 3][1] = *(const float4*)(_p + 4); \
    creg[(C) & 3][2] = *(const float4*)(_p + 8); \
    creg[(C) & 3][3] = *(const float4*)(_p + 12); } while (0)
#define WRITECH(C) do { \
    _Float16* _d = xch + (((C) & 3) * 32 + cr_row) * 136 + cr_col; \
    f16x8 _h; float4 _a, _b4; \
    _a = creg[(C) & 3][0]; _b4 = creg[(C) & 3][1]; \
    _h[0]=(_Float16)_a.x; _h[1]=(_Float16)_a.y; _h[2]=(_Float16)_a.z; _h[3]=(_Float16)_a.w; \
    _h[4]=(_Float16)_b4.x; _h[5]=(_Float16)_b4.y; _h[6]=(_Float16)_b4.z; _h[7]=(_Float16)_b4.w; \
    *(f16x8*)_d = _h; \
    _a = creg[(C) & 3][2]; _b4 = creg[(C) & 3][3]; \
    _h[0]=(_Float16)_a.x; _h[1]=(_Float16)_a.y; _h[2]=(_Float16)_a.z; _h[3]=(_Float16)_a.w; \
    _h[4]=(_Float16)_b4.x; _h[5]=(_Float16)_b4.y; _h[6]=(_Float16)_b4.z; _h[7]=(_Float16)_b4.w; \
    *(f16x8*)(_d + 8) = _h; } while (0)
#define LOADB8(DST, PTR, STR) do { \
    const _Float16* _q = (PTR) + (size_t)(w * 16 + lr) * (STR) + lg * 8; \
    _Pragma("unroll") \
    for (int _i = 0; _i < 8; ++_i) DST[_i] = *(const f16x8*)(_q + _i * 32); } while (0)
#define LOADB4(DST, PTR, STR, K0) do { \
    const _Float16* _q = (PTR) + (size_t)(w * 16 + lr) * (STR) + lg * 8; \
    _Pragma("unroll") \
    for (int _i = 0; _i < 4; ++_i) DST[_i] = *(const f16x8*)(_q + ((K0) + _i) * 32); } while (0)
#define WCOMP(XBASE, NKK0, NKK, BUSE, INIT, STOREY, BIAS, DBASE) do { \
    if (INIT) { acc0 = (f32x4){0.f,0.f,0.f,0.f}; acc1 = acc0; } \
    _Pragma("unroll") \
    for (int _kk = 0; _kk < (NKK); ++_kk) { \
        int _cg = (XBASE) + ((NKK0) + _kk) * 32 + lg * 8; \
        int _sl = (_cg >> 7) & 3, _off = _cg & 127; \
        const _Float16* _pa = xch + (_sl * 32 + lr) * 136 + _off; \
        f16x8 _A0 = *(const f16x8*)_pa; \
        f16x8 _A1 = *(const f16x8*)(_pa + 16 * 136); \
        acc0 = MFMA16(_A0, BUSE[_kk], acc0); \
        acc1 = MFMA16(_A1, BUSE[_kk], acc1); \
    } \
    if (STOREY) { \
        float _bv = (BIAS)[w * 16 + lr]; \
        _Pragma("unroll") \
        for (int _j = 0; _j < 4; ++_j) { \
            float _v0 = acc0[_j] + _bv; _v0 = _v0 > 0.f ? _v0 : 0.f; \
            ysm[(lg * 4 + _j) * 264 + (DBASE) + w * 16 + lr] = (_Float16)_v0; \
            float _v1 = acc1[_j] + _bv; _v1 = _v1 > 0.f ? _v1 : 0.f; \
            ysm[(16 + lg * 4 + _j) * 264 + (DBASE) + w * 16 + lr] = (_Float16)_v1; \
        } \
    } } while (0)
#define L2COMP(BUSE, G) do { \
    acc0 = (f32x4){0.f,0.f,0.f,0.f}; acc1 = acc0; \
    _Pragma("unroll") \
    for (int _kk = 0; _kk < 8; ++_kk) { \
        int _kl = _kk * 32 + lg * 8; \
        const _Float16* _pa = ysm + lr * 264 + _kl; \
        f16x8 _A0 = *(const f16x8*)_pa; \
        f16x8 _A1 = *(const f16x8*)(_pa + 16 * 264); \
        acc0 = MFMA16(_A0, BUSE[_kk], acc0); \
        acc1 = MFMA16(_A1, BUSE[_kk], acc1); \
    } \
    { float _bv = b2[(G) * 64 + w * 16 + lr]; \
      _Pragma("unroll") \
      for (int _j = 0; _j < 4; ++_j) { \
        float _v0 = acc0[_j] + _bv; _v0 = _v0 > 0.f ? _v0 : 0.f; \
        zsm[(lg * 4 + _j) * 264 + (G) * 64 + w * 16 + lr] = (_Float16)_v0; \
        float _v1 = acc1[_j] + _bv; _v1 = _v1 > 0.f ? _v1 : 0.f; \
        zsm[(16 + lg * 4 + _j) * 264 + (G) * 64 + w * 16 + lr] = (_Float16)_v1; \
      } } } while (0)
#define WPH(K, BU, BL, NPTR, NSTR) do { \
    WRITECH((K) + 1); \
    if ((K) <= 12) ISSUE((K) + 4); \
    PH_TOP(); \
    WCOMP(128 * (K), 0, 8, BU, true, true, b1 + (K) * 64, ((K) & 3) * 64); \
    LOADB8(BL, NPTR, NSTR); } while (0)

    ISSUE(0); ISSUE(1); ISSUE(2);
    WRITECH(0);
    ISSUE(3);
    LOADB8(Ba, wsW1, 256);

    WPH(0,  Ba, Bb, wsW1 + 1 * 16384, 256);
    WPH(1,  Bb, Ba, wsW1 + 2 * 16384, 256);
    WPH(2,  Ba, Bb, wsW1 + 3 * 16384, 256);
    WPH(3,  Bb, Ba, wsW2 + 0 * 16384, 256);
    PH_TOP(); L2COMP(Ba, 0); LOADB8(Bb, wsW1 + 4 * 16384, 256);
    WPH(4,  Bb, Ba, wsW1 + 5 * 16384, 256);
    WPH(5,  Ba, Bb, wsW1 + 6 * 16384, 256);
    WPH(6,  Bb, Ba, wsW1 + 7 * 16384, 256);
    WPH(7,  Ba, Bb, wsW2 + 1 * 16384, 256);
    PH_TOP(); L2COMP(Bb, 1); LOADB8(Ba, wsW1 + 8 * 16384, 256);
    WPH(8,  Ba, Bb, wsW1 + 9 * 16384, 256);
    WPH(9,  Bb, Ba, wsW1 + 10 * 16384, 256);
    WPH(10, Ba, Bb, wsW1 + 11 * 16384, 256);
    WPH(11, Bb, Ba, wsW2 + 2 * 16384, 256);
    PH_TOP(); L2COMP(Ba, 2); LOADB8(Bb, wsW1 + 12 * 16384, 256);
    WPH(12, Bb, Ba, wsW1 + 13 * 16384, 256);
    WPH(13, Ba, Bb, wsW1 + 14 * 16384, 256);
    WPH(14, Bb, Ba, wsW16, 384);
    WRITECH(16);
    PH_TOP();
    WCOMP(1816, 0, 8, Ba, true, false, b16, 192);
    LOADB4(Bb, wsW16, 384, 8);
    PH_TOP();
    WCOMP(1816, 8, 4, Bb, false, true, b16, 192);
    LOADB8(Ba, wsW2 + 3 * 16384, 256);
    PH_TOP(); L2COMP(Ba, 3);

    PH_TOP();
    {
        f16x8 az0[8], az1[8];
        #pragma unroll
        for (int kk = 0; kk < 8; ++kk) {
            const _Float16* pz = zsm + lr * 264 + kk * 32 + lg * 8;
            az0[kk] = *(const f16x8*)pz;
            az1[kk] = *(const f16x8*)(pz + 16 * 264);
        }
        #pragma unroll 1
        for (int t = w; t < 17; t += 4) {
            f32x4 c0 = {0.f,0.f,0.f,0.f}, c1 = {0.f,0.f,0.f,0.f};
            #pragma unroll
            for (int kk = 0; kk < 8; ++kk) {
                f16x8 B = *(const f16x8*)(wsW3 + (size_t)(t * 16 + lr) * 256 + kk * 32 + lg * 8);
                c0 = MFMA16(az0[kk], B, c0);
                c1 = MFMA16(az1[kk], B, c1);
            }
            int o = t * 16 + lr;
            float bv = (o < 260) ? b3[o] : 0.f;
            #pragma unroll
            for (int j2 = 0; j2 < 4; ++j2) {
                float v0 = c0[j2] + bv; v0 = v0 > 0.f ? v0 : 0.f;
                hsm[(lg * 4 + j2) * 280 + o] = v0;
                float v1 = c1[j2] + bv; v1 = v1 > 0.f ? v1 : 0.f;
                hsm[(16 + lg * 4 + j2) * 280 + o] = v1;
            }
        }
    }
    PH_TOP();

    if (tid < 32) {
        int row = tid;
        float p[10];
        #pragma unroll
        for (int c = 0; c < 10; ++c) {
            float s = 0.f;
            #pragma unroll
            for (int u = 0; u < 26; ++u) s += hsm[row * 280 + c * 26 + u];
            p[c] = s;
        }
        float m = p[0];
        #pragma unroll
        for (int c = 1; c < 10; ++c) m = fmaxf(m, p[c]);
        float e[10], se = 0.f;
        #pragma unroll
        for (int c = 0; c < 10; ++c) { e[c] = expf(p[c] - m); se += e[c]; }
        float inv = 1.f / se;
        float* orow = out + (size_t)(bid * 32 + row) * 10;
        #pragma unroll
        for (int c = 0; c < 10; ++c) orow[c] = e[c] * inv;
    }
#undef PH_TOP
#undef ISSUE
#undef WRITECH
#undef LOADB8
#undef LOADB4
#undef WCOMP
#undef L2COMP
#undef WPH
}

extern "C" void kernel_launch(void* const* d_in, const int* in_sizes, int n_in,
                              void* d_out, int out_size, void* d_ws, size_t ws_size,
                              hipStream_t stream)
{
    const float* x   = (const float*)d_in[0];
    const float* W1  = (const float*)d_in[1];
    const float* b1  = (const float*)d_in[2];
    const float* W16 = (const float*)d_in[3];
    const float* b16 = (const float*)d_in[4];
    const float* W2  = (const float*)d_in[5];
    const float* b2  = (const float*)d_in[6];
    const float* W3  = (const float*)d_in[7];
    const float* b3  = (const float*)d_in[8];
    float*    out = (float*)d_out;
    _Float16* ws  = (_Float16*)d_ws;

    tea_prep<<<1584, 256, 0, stream>>>(W1, W16, W2, W3, ws);

    const size_t need = (size_t)(405504 + 16384 * 1024) * 2;
    if (ws_size >= need) {
        _Float16* y = ws + 405504;
        tea_l1 <<<3840, 256, 0, stream>>>(x, b1, ws, y);
        tea_l1b<<<256,  256, 0, stream>>>(x, b16, ws, y);
        tea_l2 <<<1024, 256, 0, stream>>>(y, b2, b3, ws, out);
    } else {
        tea_mono<<<512, 256, 0, stream>>>(x, b1, b16, b2, b3, ws, out);
    }
}

// Round 6
// 77.614 us; speedup vs baseline: 1.5057x; 1.5057x over previous
//
#include <hip/hip_runtime.h>
#include <hip/hip_bf16.h>
#include <cstdint>
#include <cstddef>

typedef _Float16 f16x8  __attribute__((ext_vector_type(8)));
typedef float    f32x4  __attribute__((ext_vector_type(4)));
typedef float    f32x16 __attribute__((ext_vector_type(16)));

#define MFMA16(a,b,c) __builtin_amdgcn_mfma_f32_16x16x32_f16((a),(b),(c),0,0,0)
#define MFMA32(a,b,c) __builtin_amdgcn_mfma_f32_32x32x16_f16((a),(b),(c),0,0,0)

// Workspace (_Float16 elems):
//   W1T  [15][64][256] at 0        (245760)
//   W16T [64][384]     at 245760   (24576)  sp: x col = 1816+sp; zero for sp<4 or sp>=360
//   W2T  [4][64][256]  at 270336   (65536)
//   W3T  [272][256]    at 335872   (69632)  rows >= 260 zero
__global__ void tea_prep(const float* __restrict__ W1, const float* __restrict__ W16,
                         const float* __restrict__ W2, const float* __restrict__ W3,
                         _Float16* __restrict__ ws)
{
    int i = blockIdx.x * blockDim.x + threadIdx.x;
    if (i < 245760) {
        int k = i >> 14, r = i & 16383, o = r >> 8, s = r & 255;
        ws[i] = (_Float16)W1[((k << 8) | s) * 64 + o];
    } else if (i < 270336) {
        int r = i - 245760, o = r / 384, sp = r - o * 384;
        float v = (sp >= 4 && sp < 360) ? W16[(sp - 4) * 64 + o] : 0.f;
        ws[i] = (_Float16)v;
    } else if (i < 335872) {
        int r = i - 270336, g = r >> 14, rr = r & 16383, o = rr >> 8, s = rr & 255;
        ws[i] = (_Float16)W2[((g << 8) | s) * 64 + o];
    } else if (i < 405504) {
        int r = i - 335872, o = r >> 8, s = r & 255;
        ws[i] = (_Float16)((o < 260) ? W3[s * 260 + o] : 0.f);
    }
}

// LDS (78592 B -> 2 blocks/CU):
//   ring [5][32][140] f16 at 0      (44800 B)  5-slot ring of 128-col x chunks
//   ysm  [32][264]    f16 at 22400h (16896 B)  current group's y
//   zsm  [32][264]    f16 at 30848h (16896 B)  z
//   phase B: hsm [32][280] f32 at 0 (35840 B)  aliases ring
// Ring hazard discipline: ring slots are written ONLY between barrier A and
// barrier B of a pair phase (all prior readers proven done by barrier A;
// writes published by barrier B).  Neither barrier drains vmcnt.
__global__ __launch_bounds__(256, 2)
void tea_main(const float* __restrict__ x,
              const float* __restrict__ b1,
              const float* __restrict__ b16,
              const float* __restrict__ b2,
              const float* __restrict__ b3,
              const _Float16* __restrict__ ws,
              float* __restrict__ out)
{
    __shared__ _Float16 lds[39296];
    _Float16* ring = lds;               // [5][32][140]
    _Float16* ysm  = lds + 22400;       // [32][264]
    _Float16* zsm  = lds + 30848;       // [32][264]
    float*    hsm  = (float*)lds;       // [32][280] (epilogue only)

    const int tid  = threadIdx.x;
    const int bid  = blockIdx.x;
    const int w    = tid >> 6;
    const int l    = tid & 63;
    const int lo   = l & 31;           // 32x32 row/col lane index
    const int hi8  = (l >> 5) * 8;     // 32x32 k lane-group offset
    const int lg4  = l >> 4;           // 16x16 k group (0..3)
    const int lr16 = l & 15;           // 16x16 row/col lane
    const int cb   = (w & 1) * 32;     // col base within a 64-col window

    const _Float16* wsW1  = ws;
    const _Float16* wsW16 = ws + 245760;
    const _Float16* wsW2  = ws + 270336;
    const _Float16* wsW3  = ws + 335872;

    const float* xrow = x + (size_t)bid * 32 * 2176;
    const int crow = tid >> 3;          // 0..31
    const int ccol = (tid & 7) * 16;    // 0..112

    float4 cregE[4], cregO[4];          // even / odd chunk in flight
    f16x8  Bwin[16], BL2[8];

#define PH_TOP() do { \
    asm volatile("s_waitcnt lgkmcnt(0)" ::: "memory"); \
    __builtin_amdgcn_s_barrier(); \
    __builtin_amdgcn_sched_barrier(0); } while (0)

#define ISSUE(C, R) do { \
    const float* _p = xrow + (size_t)crow * 2176 + (C) * 128 + ccol; \
    R[0] = *(const float4*)(_p);      R[1] = *(const float4*)(_p + 4); \
    R[2] = *(const float4*)(_p + 8);  R[3] = *(const float4*)(_p + 12); } while (0)

#define WRITECH(C, R) do { \
    _Float16* _d = ring + ((C) % 5) * 4480 + crow * 140 + ccol; \
    f16x8 _h; float4 _a, _b4; \
    _a = R[0]; _b4 = R[1]; \
    _h[0]=(_Float16)_a.x; _h[1]=(_Float16)_a.y; _h[2]=(_Float16)_a.z; _h[3]=(_Float16)_a.w; \
    _h[4]=(_Float16)_b4.x; _h[5]=(_Float16)_b4.y; _h[6]=(_Float16)_b4.z; _h[7]=(_Float16)_b4.w; \
    *(f16x8*)_d = _h; \
    _a = R[2]; _b4 = R[3]; \
    _h[0]=(_Float16)_a.x; _h[1]=(_Float16)_a.y; _h[2]=(_Float16)_a.z; _h[3]=(_Float16)_a.w; \
    _h[4]=(_Float16)_b4.x; _h[5]=(_Float16)_b4.y; _h[6]=(_Float16)_b4.z; _h[7]=(_Float16)_b4.w; \
    *(f16x8*)(_d + 8) = _h; } while (0)

    // A-frag for window WIN (compile-time), kk 0..15: chunk = WIN + (kk>=8), all folds
#define AFRAG(WIN, KK) \
    (*(const f16x8*)(ring + (((WIN) + ((KK) >= 8)) % 5) * 4480 + lo * 140 + ((KK) & 7) * 16 + hi8))

    // y16 A-frag: global col 1816 + kk*16 + hi8; chunks 14..16 live in slots 4,0,1;
    // chunk "17" (sp>=360) reads stale slot 2 -> finite garbage x zero weights
#define AY16(KK) ({ \
    int _cg = 1816 + (KK) * 16 + hi8; int _ch = _cg >> 7; \
    int _sl = (_ch >= 15) ? (_ch - 15) : 4; \
    *(const f16x8*)(ring + _sl * 4480 + lo * 140 + (_cg & 127)); })

#define LOADBWIN(WIN) do { \
    const _Float16* _q = wsW1 + (WIN) * 16384 + (size_t)(cb + lo) * 256 + hi8; \
    _Pragma("unroll") for (int _i = 0; _i < 16; ++_i) Bwin[_i] = *(const f16x8*)(_q + _i * 16); } while (0)

#define LOADB16F() do { \
    const _Float16* _q = wsW16 + (size_t)(cb + lo) * 384 + hi8; \
    _Pragma("unroll") for (int _i = 0; _i < 16; ++_i) Bwin[_i] = *(const f16x8*)(_q + _i * 16); } while (0)

#define LOADBL2(G) do { \
    const _Float16* _q = wsW2 + (G) * 16384 + (size_t)(w * 16 + lr16) * 256 + lg4 * 8; \
    _Pragma("unroll") for (int _i = 0; _i < 8; ++_i) BL2[_i] = *(const f16x8*)(_q + _i * 32); } while (0)

    // 32x32 C/D: col = lo, row = (r&3) + 8*(r>>2) + 4*(l>>5)   [m74/m101-verified]
#define WCOMP32(WIN, BIASP) do { \
    f32x16 _acc; _Pragma("unroll") for (int _i = 0; _i < 16; ++_i) _acc[_i] = 0.f; \
    _Pragma("unroll") for (int _kk = 0; _kk < 16; ++_kk) \
        _acc = MFMA32(AFRAG(WIN, _kk), Bwin[_kk], _acc); \
    float _bv = (BIASP)[cb + lo]; \
    _Float16* _yo = ysm + ((WIN) & 3) * 64 + cb + lo; \
    _Pragma("unroll") for (int _r = 0; _r < 16; ++_r) { \
        int _row = (_r & 3) + 8 * (_r >> 2) + ((l >> 5) << 2); \
        float _v = _acc[_r] + _bv; _v = _v > 0.f ? _v : 0.f; \
        _yo[_row * 264] = (_Float16)_v; } } while (0)

#define WCOMPY16() do { \
    f32x16 _acc; _Pragma("unroll") for (int _i = 0; _i < 16; ++_i) _acc[_i] = 0.f; \
    _Pragma("unroll") for (int _kk = 0; _kk < 16; ++_kk) \
        _acc = MFMA32(AY16(_kk), Bwin[_kk], _acc); \
    _Pragma("unroll") for (int _kk = 16; _kk < 23; ++_kk) { \
        f16x8 _B = *(const f16x8*)(wsW16 + (size_t)(cb + lo) * 384 + _kk * 16 + hi8); \
        _acc = MFMA32(AY16(_kk), _B, _acc); } \
    float _bv = b16[cb + lo]; \
    _Float16* _yo = ysm + 192 + cb + lo; \
    _Pragma("unroll") for (int _r = 0; _r < 16; ++_r) { \
        int _row = (_r & 3) + 8 * (_r >> 2) + ((l >> 5) << 2); \
        float _v = _acc[_r] + _bv; _v = _v > 0.f ? _v : 0.f; \
        _yo[_row * 264] = (_Float16)_v; } } while (0)

#define L2COMP(G) do { \
    f32x4 _a0 = {0.f,0.f,0.f,0.f}, _a1 = {0.f,0.f,0.f,0.f}; \
    _Pragma("unroll") for (int _kk = 0; _kk < 8; ++_kk) { \
        const _Float16* _pa = ysm + lr16 * 264 + _kk * 32 + lg4 * 8; \
        f16x8 _A0 = *(const f16x8*)_pa; \
        f16x8 _A1 = *(const f16x8*)(_pa + 16 * 264); \
        _a0 = MFMA16(_A0, BL2[_kk], _a0); \
        _a1 = MFMA16(_A1, BL2[_kk], _a1); } \
    float _bv = b2[(G) * 64 + w * 16 + lr16]; \
    _Pragma("unroll") for (int _j = 0; _j < 4; ++_j) { \
        float _v0 = _a0[_j] + _bv; _v0 = _v0 > 0.f ? _v0 : 0.f; \
        zsm[(lg4 * 4 + _j) * 264 + (G) * 64 + w * 16 + lr16] = (_Float16)_v0; \
        float _v1 = _a1[_j] + _bv; _v1 = _v1 > 0.f ? _v1 : 0.f; \
        zsm[(16 + lg4 * 4 + _j) * 264 + (G) * 64 + w * 16 + lr16] = (_Float16)_v1; } } while (0)

    // pair phase P:
    //   [barrier A]  (all readers of the ring are done)
    //   WRITECH chunks 2P+3, 2P+4
    //   [barrier B]  (writes published)
    //   ISSUE chunks 2P+5, 2P+6 (stay in flight through this phase's compute)
    //   compute window pair (w<2: win 2P; w>=2: win 2P+1) + prefetch next B regs
#define PAIRPH(P, HASL2, G) do { \
    PH_TOP(); \
    if ((P) <= 6) { \
        WRITECH(2*(P)+3, cregO); WRITECH(2*(P)+4, cregE); \
        PH_TOP(); \
    } \
    if ((P) <= 5) { ISSUE(2*(P)+5, cregO); ISSUE(2*(P)+6, cregE); } \
    if (HASL2) LOADBL2(G); \
    if ((P) < 7) { \
        if (w < 2) { WCOMP32(2*(P), b1 + 2*(P)*64); LOADBWIN(2*(P)+2); } \
        else { \
            WCOMP32(2*(P)+1, b1 + (2*(P)+1)*64); \
            if ((P) < 6) { LOADBWIN(2*(P)+3); } else { LOADB16F(); } } \
    } else { \
        if (w < 2) { WCOMP32(14, b1 + 14*64); } \
        else       { WCOMPY16(); } } } while (0)

#define L2PH(G) do { PH_TOP(); L2COMP(G); } while (0)

    // ---- prologue: chunks 0..2 staged, 3,4 in regs, Bwin(pair0) in flight ----
    ISSUE(0, cregE); ISSUE(1, cregO);
    WRITECH(0, cregE); WRITECH(1, cregO);
    ISSUE(2, cregE); ISSUE(3, cregO);
    WRITECH(2, cregE);
    ISSUE(4, cregE);
    if (w < 2) { LOADBWIN(0); } else { LOADBWIN(1); }

    PAIRPH(0, 0, 0);
    PAIRPH(1, 1, 0);  L2PH(0);
    PAIRPH(2, 0, 0);
    PAIRPH(3, 1, 1);  L2PH(1);
    PAIRPH(4, 0, 0);
    PAIRPH(5, 1, 2);  L2PH(2);
    PAIRPH(6, 0, 0);
    PAIRPH(7, 1, 3);  L2PH(3);

    // ---- layer 3: wave w does col-tiles t = w, w+4, ...; B from L2 ----
    PH_TOP();
    {
        f16x8 az0[8], az1[8];
        #pragma unroll
        for (int kk = 0; kk < 8; ++kk) {
            const _Float16* pz = zsm + lr16 * 264 + kk * 32 + lg4 * 8;
            az0[kk] = *(const f16x8*)pz;
            az1[kk] = *(const f16x8*)(pz + 16 * 264);
        }
        #pragma unroll 1
        for (int t = w; t < 17; t += 4) {
            f32x4 c0 = {0.f,0.f,0.f,0.f}, c1 = {0.f,0.f,0.f,0.f};
            #pragma unroll
            for (int kk = 0; kk < 8; ++kk) {
                f16x8 B = *(const f16x8*)(wsW3 + (size_t)(t * 16 + lr16) * 256 + kk * 32 + lg4 * 8);
                c0 = MFMA16(az0[kk], B, c0);
                c1 = MFMA16(az1[kk], B, c1);
            }
            int o = t * 16 + lr16;
            float bv = (o < 260) ? b3[o] : 0.f;
            #pragma unroll
            for (int j2 = 0; j2 < 4; ++j2) {
                float v0 = c0[j2] + bv; v0 = v0 > 0.f ? v0 : 0.f;
                hsm[(lg4 * 4 + j2) * 280 + o] = v0;
                float v1 = c1[j2] + bv; v1 = v1 > 0.f ? v1 : 0.f;
                hsm[(16 + lg4 * 4 + j2) * 280 + o] = v1;
            }
        }
    }
    PH_TOP();

    // ---- pooling (10 x 26) + softmax; threads 0..31 each own one row ----
    if (tid < 32) {
        int row = tid;
        float p[10];
        #pragma unroll
        for (int c = 0; c < 10; ++c) {
            float s = 0.f;
            #pragma unroll
            for (int u = 0; u < 26; ++u) s += hsm[row * 280 + c * 26 + u];
            p[c] = s;
        }
        float m = p[0];
        #pragma unroll
        for (int c = 1; c < 10; ++c) m = fmaxf(m, p[c]);
        float e[10], se = 0.f;
        #pragma unroll
        for (int c = 0; c < 10; ++c) { e[c] = expf(p[c] - m); se += e[c]; }
        float inv = 1.f / se;
        float* orow = out + (size_t)(bid * 32 + row) * 10;
        #pragma unroll
        for (int c = 0; c < 10; ++c) orow[c] = e[c] * inv;
    }

#undef PH_TOP
#undef ISSUE
#undef WRITECH
#undef AFRAG
#undef AY16
#undef LOADBWIN
#undef LOADB16F
#undef LOADBL2
#undef WCOMP32
#undef WCOMPY16
#undef L2COMP
#undef PAIRPH
#undef L2PH
}

extern "C" void kernel_launch(void* const* d_in, const int* in_sizes, int n_in,
                              void* d_out, int out_size, void* d_ws, size_t ws_size,
                              hipStream_t stream)
{
    const float* x   = (const float*)d_in[0];
    const float* W1  = (const float*)d_in[1];
    const float* b1  = (const float*)d_in[2];
    const float* W16 = (const float*)d_in[3];
    const float* b16 = (const float*)d_in[4];
    const float* W2  = (const float*)d_in[5];
    const float* b2  = (const float*)d_in[6];
    const float* W3  = (const float*)d_in[7];
    const float* b3  = (const float*)d_in[8];
    float*    out = (float*)d_out;
    _Float16* ws  = (_Float16*)d_ws;

    tea_prep<<<1584, 256, 0, stream>>>(W1, W16, W2, W3, ws);
    tea_main<<<512, 256, 0, stream>>>(x, b1, b16, b2, b3, ws, out);
}